// Round 14
// baseline (208.308 us; speedup 1.0000x reference)
//
#include <hip/hip_runtime.h>
#include <stdint.h>

typedef __attribute__((ext_vector_type(8))) short  s16x8;
typedef __attribute__((ext_vector_type(4))) float  f32x4;
typedef __attribute__((ext_vector_type(4))) unsigned short u16x4;

__device__ __forceinline__ unsigned short f2bf(float f) {
  union { float f; uint32_t u; } x; x.f = f;
  uint32_t u = x.u;
  return (unsigned short)((u + 0x7fffu + ((u >> 16) & 1u)) >> 16);
}

__device__ __forceinline__ float fexp2(float x) {
  float r; asm("v_exp_f32 %0, %1" : "=v"(r) : "v"(x)); return r;
}
__device__ __forceinline__ uint32_t cvtpk_bf16(float lo, float hi) {
  uint32_t r; asm("v_cvt_pk_bf16_f32 %0, %1, %2" : "=v"(r) : "v"(lo), "v"(hi)); return r;
}

__device__ __forceinline__ void gload_lds16(const void* g, void* l) {
  __builtin_amdgcn_global_load_lds(
      (const __attribute__((address_space(1))) void*)g,
      (__attribute__((address_space(3))) void*)l, 16, 0, 0);
}

#define PBAR() { asm volatile("" ::: "memory"); __builtin_amdgcn_s_barrier(); }

// ---------------- fused fp32 -> bf16 converts (7 jobs, one launch) ----------
struct CvtJobs {
  const float* src[7];
  unsigned short* dst[7];
  int n4[7];
};
__global__ __launch_bounds__(256) void cvt_all(CvtJobs jobs) {
  const int j = blockIdx.y;
  const float* __restrict__ src = jobs.src[j];
  unsigned short* __restrict__ dst = jobs.dst[j];
  const int n4 = jobs.n4[j];
  const int stride = gridDim.x * blockDim.x;
  for (int i = blockIdx.x * blockDim.x + threadIdx.x; i < n4; i += stride) {
    f32x4 v = *(const f32x4*)(src + (size_t)i * 4);
    u16x4 o = { f2bf(v[0]), f2bf(v[1]), f2bf(v[2]), f2bf(v[3]) };
    *(u16x4*)(dst + (size_t)i * 4) = o;
  }
}

// ---------------- 256x256 bf16 GEMM core (C = A @ B^T), BK=64 --------------
// 8 waves (2Mx4N), wave tile 128x64, acc[8][4]. 2 LDS buffers (2x64KB=128KB).
// 4 phases per K-tile, 16 MFMA each; counted vmcnt(4) once per tile (tile t+1
// fully resident, tile t+2's A in flight); A-halves staged into OWN buffer at
// P4 (all A/B reads of tile t fenced complete at P3's lgkmcnt(0)); B-halves
// staged into the other buffer at P1/P2. 8-chunk XOR swizzle both sides.
struct GemmJob {
  const unsigned short* A;
  const unsigned short* Bmat;
  const float* bias;
  unsigned short* C;
  int M, N, Nb;
  int bias_row;
  float scale;
};

__device__ __forceinline__ void gemm_core256(const unsigned short* __restrict__ A,
                                             const unsigned short* __restrict__ Bw,
                                             int m0, int n0, int K, char* L,
                                             f32x4 (&acc)[8][4]) {
  const int tid = threadIdx.x;            // 0..511
  const int l = tid & 63;
  const int lr = l & 15, lc = l >> 4;
  const int w = tid >> 6;                 // 0..7
  const int wr = w >> 2, wc = w & 3;      // 2 x 4

  // staging: half = 128 rows x 64 cols (16KB) = 512 thr x 2 x 16B
  const int srow = tid >> 3;              // 0..63
  const int sc = (tid & 7) ^ (srow & 7);  // pre-swizzled source chunk (rows r, r+64 share)
  const unsigned short* sa0 = A + (size_t)(m0 + srow) * K + sc * 8;         // A half0 rows
  const unsigned short* sa1 = A + (size_t)(m0 + 128 + srow) * K + sc * 8;   // A half1
  const unsigned short* sb0 = Bw + (size_t)(n0 + srow) * K + sc * 8;
  const unsigned short* sb1 = Bw + (size_t)(n0 + 128 + srow) * K + sc * 8;
  const size_t rk64 = (size_t)64 * K;     // +64 rows
  char* dst0 = L + (size_t)tid * 16;      // first 64 rows of a half
  // layout: buf*65536 + (B?32768:0) + half*16384 + sub*8192 + tid*16

#define STGA(BUF, H, KT) { \
    const unsigned short* s_ = (H) ? sa1 : sa0; \
    gload_lds16(s_ + (size_t)(KT) * 64,        dst0 + (BUF) * 65536 + (H) * 16384); \
    gload_lds16(s_ + rk64 + (size_t)(KT) * 64, dst0 + (BUF) * 65536 + (H) * 16384 + 8192); }
#define STGB(BUF, H, KT) { \
    const unsigned short* s_ = (H) ? sb1 : sb0; \
    gload_lds16(s_ + (size_t)(KT) * 64,        dst0 + (BUF) * 65536 + 32768 + (H) * 16384); \
    gload_lds16(s_ + rk64 + (size_t)(KT) * 64, dst0 + (BUF) * 65536 + 32768 + (H) * 16384 + 8192); }

  // fragment byte offsets: row*128 + ((ks*4+lc)^(lr&7))*16
  const int c0 = ((lc) ^ (lr & 7)) << 4;
  const int c1 = ((4 + lc) ^ (lr & 7)) << 4;
  int offA[8], offB[4];
#pragma unroll
  for (int i = 0; i < 8; ++i) offA[i] = (wr * 128 + i * 16 + lr) * 128;
#pragma unroll
  for (int j = 0; j < 4; ++j) offB[j] = 32768 + (wc * 64 + j * 16 + lr) * 128;

  const int nk = K >> 6;                  // 16
  // prologue: tile0 fully staged; tile1's A halves in flight
  STGA(0, 0, 0); STGA(0, 1, 0); STGB(0, 0, 0); STGB(0, 1, 0);
  STGA(1, 0, 1); STGA(1, 1, 1);
  asm volatile("s_waitcnt vmcnt(4)" ::: "memory");
  __builtin_amdgcn_s_barrier();

  for (int t = 0; t < nk; ++t) {
    const int buf = t & 1;
    const char* Lb = L + buf * 65536;
    s16x8 a0[8], b0[4], a1[8], b1[4];

    // ---- P1: stage t+1.B0 ; read ks0 frags ; MFMA n0-1 x ks0 ----
    if (t + 1 < nk) STGB(buf ^ 1, 0, t + 1);
#pragma unroll
    for (int i = 0; i < 8; ++i) a0[i] = *(const s16x8*)(Lb + offA[i] + c0);
#pragma unroll
    for (int j = 0; j < 4; ++j) b0[j] = *(const s16x8*)(Lb + offB[j] + c0);
    __builtin_amdgcn_s_setprio(1);
#pragma unroll
    for (int i = 0; i < 8; ++i) {
      acc[i][0] = __builtin_amdgcn_mfma_f32_16x16x32_bf16(a0[i], b0[0], acc[i][0], 0, 0, 0);
      acc[i][1] = __builtin_amdgcn_mfma_f32_16x16x32_bf16(a0[i], b0[1], acc[i][1], 0, 0, 0);
    }
    __builtin_amdgcn_s_setprio(0);
    PBAR();

    // ---- P2: stage t+1.B1 ; MFMA n2-3 x ks0 ----
    if (t + 1 < nk) STGB(buf ^ 1, 1, t + 1);
    __builtin_amdgcn_s_setprio(1);
#pragma unroll
    for (int i = 0; i < 8; ++i) {
      acc[i][2] = __builtin_amdgcn_mfma_f32_16x16x32_bf16(a0[i], b0[2], acc[i][2], 0, 0, 0);
      acc[i][3] = __builtin_amdgcn_mfma_f32_16x16x32_bf16(a0[i], b0[3], acc[i][3], 0, 0, 0);
    }
    __builtin_amdgcn_s_setprio(0);
    PBAR();

    // ---- P3: read ks1 frags ; MFMA n0-1 x ks1 ; fence all tile-t LDS reads ----
#pragma unroll
    for (int i = 0; i < 8; ++i) a1[i] = *(const s16x8*)(Lb + offA[i] + c1);
#pragma unroll
    for (int j = 0; j < 4; ++j) b1[j] = *(const s16x8*)(Lb + offB[j] + c1);
    __builtin_amdgcn_s_setprio(1);
#pragma unroll
    for (int i = 0; i < 8; ++i) {
      acc[i][0] = __builtin_amdgcn_mfma_f32_16x16x32_bf16(a1[i], b1[0], acc[i][0], 0, 0, 0);
      acc[i][1] = __builtin_amdgcn_mfma_f32_16x16x32_bf16(a1[i], b1[1], acc[i][1], 0, 0, 0);
    }
    __builtin_amdgcn_s_setprio(0);
    asm volatile("s_waitcnt lgkmcnt(0)" ::: "memory");
    __builtin_amdgcn_s_barrier();

    // ---- P4: stage t+2.A0,A1 into OWN buf (reads done) ; MFMA n2-3 x ks1 ----
    if (t + 2 < nk) { STGA(buf, 0, t + 2); STGA(buf, 1, t + 2); }
    __builtin_amdgcn_s_setprio(1);
#pragma unroll
    for (int i = 0; i < 8; ++i) {
      acc[i][2] = __builtin_amdgcn_mfma_f32_16x16x32_bf16(a1[i], b1[2], acc[i][2], 0, 0, 0);
      acc[i][3] = __builtin_amdgcn_mfma_f32_16x16x32_bf16(a1[i], b1[3], acc[i][3], 0, 0, 0);
    }
    __builtin_amdgcn_s_setprio(0);
    if (t + 2 < nk) asm volatile("s_waitcnt vmcnt(4)" ::: "memory");
    else            asm volatile("s_waitcnt vmcnt(0)" ::: "memory");
    __builtin_amdgcn_s_barrier();
  }
#undef STGA
#undef STGB
}

// fused Q/K/V projection GEMMs, XCD-chunked 1D grid (384 blocks)
__global__ __launch_bounds__(512) void gemm_qkv(GemmJob j0, GemmJob j1, GemmJob j2) {
  __shared__ __align__(16) char L[131072];
  const int f = blockIdx.x;
  const int wid = (f & 7) * 48 + (f >> 3);
  const int job = wid >> 7;               // 128 tiles per job
  const int i = wid & 127;
  const GemmJob jb = (job == 0) ? j0 : (job == 1) ? j1 : j2;
  const int m0 = (i / jb.Nb) * 256, n0 = (i % jb.Nb) * 256;
  f32x4 acc[8][4];
#pragma unroll
  for (int i2 = 0; i2 < 8; ++i2)
#pragma unroll
    for (int j2 = 0; j2 < 4; ++j2) acc[i2][j2] = (f32x4){0.f, 0.f, 0.f, 0.f};
  gemm_core256(jb.A, jb.Bmat, m0, n0, 1024, L, acc);
  const int tid = threadIdx.x;
  const int l = tid & 63, w = tid >> 6;
  const int lr = l & 15, lc = l >> 4;
  const int wr = w >> 2, wc = w & 3;
#pragma unroll
  for (int i2 = 0; i2 < 8; ++i2) {
    const int row0 = m0 + wr * 128 + i2 * 16 + lc * 4;
    f32x4 brow;
    if (jb.bias_row) brow = *(const f32x4*)&jb.bias[row0];
#pragma unroll
    for (int j2 = 0; j2 < 4; ++j2) {
      const int col = n0 + wc * 64 + j2 * 16 + lr;
      float bcol = jb.bias_row ? 0.f : jb.bias[col];
#pragma unroll
      for (int r = 0; r < 4; ++r) {
        float v = (acc[i2][j2][r] + (jb.bias_row ? brow[r] : bcol)) * jb.scale;
        jb.C[(size_t)(row0 + r) * jb.N + col] = f2bf(v);
      }
    }
  }
}

// output projection GEMM (fp32 out, col bias), XCD-chunked 1D grid (128)
__global__ __launch_bounds__(512) void gemm_out(const unsigned short* __restrict__ A,
                                                const unsigned short* __restrict__ Bw,
                                                const float* __restrict__ bias,
                                                float* __restrict__ Cout,
                                                int M, int N, int K) {
  __shared__ __align__(16) char L[131072];
  const int f = blockIdx.x;
  const int wid = (f & 7) * 16 + (f >> 3);
  const int m0 = (wid >> 2) * 256, n0 = (wid & 3) * 256;
  f32x4 acc[8][4];
#pragma unroll
  for (int i = 0; i < 8; ++i)
#pragma unroll
    for (int j = 0; j < 4; ++j) acc[i][j] = (f32x4){0.f, 0.f, 0.f, 0.f};
  gemm_core256(A, Bw, m0, n0, K, L, acc);
  const int tid = threadIdx.x;
  const int l = tid & 63, w = tid >> 6;
  const int lr = l & 15, lc = l >> 4;
  const int wr = w >> 2, wc = w & 3;
#pragma unroll
  for (int i = 0; i < 8; ++i) {
    const int row0 = m0 + wr * 128 + i * 16 + lc * 4;
#pragma unroll
    for (int j = 0; j < 4; ++j) {
      const int col = n0 + wc * 64 + j * 16 + lr;
      float bcol = bias[col];
#pragma unroll
      for (int r = 0; r < 4; ++r)
        Cout[(size_t)(row0 + r) * N + col] = acc[i][j][r] + bcol;
    }
  }
}

// ---------------- flash attention: B=4,S=2048,H=16,HD=64 ----------------
// (unchanged from R13 — issue-saturated at 46% Mfma + 46% VALU)
__global__ __launch_bounds__(512) void attn_fwd(const unsigned short* __restrict__ qb,
                                                const unsigned short* __restrict__ kb,
                                                const unsigned short* __restrict__ vtb,
                                                unsigned short* __restrict__ ob) {
  __shared__ __align__(16) unsigned short L[3 * 8192];
  const int tid = threadIdx.x;
  const int l = tid & 63, w = tid >> 6;
  const int lr = l & 15, lc = l >> 4;
  const int i0 = blockIdx.x;
  const int wid = (i0 & 7) * 128 + (i0 >> 3);
  const int qx = wid & 15;
  const int h = (wid >> 4) & 15;
  const int b = wid >> 8;
  const int q0 = qx * 128;
  const size_t qkbase = ((size_t)b * 2048) * 1024 + (size_t)h * 64;
  const size_t vtbase = (size_t)(h * 64) * 8192 + (size_t)b * 2048;

  s16x8 aq0, aq1;
  {
    const unsigned short* qp = qb + qkbase + (size_t)(q0 + w * 16 + lr) * 1024 + lc * 8;
    aq0 = *(const s16x8*)qp;
    aq1 = *(const s16x8*)(qp + 32);
  }

  union { u16x4 h4[2]; s16x8 v; } onesu;
#pragma unroll
  for (int i = 0; i < 2; ++i) onesu.h4[i] = (u16x4){0x3F80, 0x3F80, 0x3F80, 0x3F80};
  const s16x8 bones = onesu.v;

  f32x4 oacc[4];
  f32x4 oextra = (f32x4){0.f, 0.f, 0.f, 0.f};
#pragma unroll
  for (int nd = 0; nd < 4; ++nd) oacc[nd] = (f32x4){0.f, 0.f, 0.f, 0.f};

  const int role = w >> 2, wk = w & 3;
  const int rl = l >> 3;
  const int cs = (l & 7) ^ rl;
  const int rA = wk * 16 + rl, rB = rA + 8;
#define RHO(rr) (8 * (((rr) >> 2) & 3) + 4 * (((rr) >> 4) & 1) + ((rr) & 3) + 32 * ((rr) >> 5))
  const unsigned short* sA;
  const unsigned short* sB;
  size_t tstep;
  if (role == 0) {
    sA = kb + qkbase + (size_t)RHO(rA) * 1024 + cs * 8;
    sB = kb + qkbase + (size_t)RHO(rB) * 1024 + cs * 8;
    tstep = (size_t)64 * 1024;
  } else {
    sA = vtb + vtbase + (size_t)rA * 8192 + cs * 8;
    sB = vtb + vtbase + (size_t)rB * 8192 + cs * 8;
    tstep = 64;
  }
#undef RHO
  char* dstL = (char*)L + role * 8192 + wk * 2048 + l * 16;

#define STAGE(BUF, T) {                                              \
    gload_lds16(sA + (size_t)(T) * tstep, dstL + (BUF) * 16384);     \
    gload_lds16(sB + (size_t)(T) * tstep, dstL + (BUF) * 16384 + 1024); }

  int off0[4];
#pragma unroll
  for (int ni = 0; ni < 4; ++ni)
    off0[ni] = (ni * 16 + lr) * 128 + ((lc ^ (lr & 7)) * 16);

  STAGE(0, 0);
  STAGE(1, 1);

  int cur = 0;
  for (int t = 0; t < 32; ++t) {
    if (t < 31) asm volatile("s_waitcnt vmcnt(2)" ::: "memory");
    else        asm volatile("s_waitcnt vmcnt(0)" ::: "memory");
    __builtin_amdgcn_s_barrier();
    if (t < 30) {
      int nb = cur + 2; if (nb >= 3) nb -= 3;
      STAGE(nb, t + 2);
    }
    const char* Lb = (const char*)L + cur * 16384;

    f32x4 sf[4];
    __builtin_amdgcn_s_setprio(1);
#pragma unroll
    for (int ni = 0; ni < 4; ++ni) {
      s16x8 k0 = *(const s16x8*)(Lb + off0[ni]);
      s16x8 k1 = *(const s16x8*)(Lb + (off0[ni] ^ 64));
      f32x4 z = (f32x4){0.f, 0.f, 0.f, 0.f};
      z = __builtin_amdgcn_mfma_f32_16x16x32_bf16(k0, aq0, z, 0, 0, 0);
      z = __builtin_amdgcn_mfma_f32_16x16x32_bf16(k1, aq1, z, 0, 0, 0);
      sf[ni] = z;
    }
    __builtin_amdgcn_s_setprio(0);

    union { uint32_t u[4]; s16x8 v; } pa0u, pa1u;
#pragma unroll
    for (int ni = 0; ni < 4; ++ni) {
      float p0 = fexp2(sf[ni][0]);
      float p1 = fexp2(sf[ni][1]);
      float p2 = fexp2(sf[ni][2]);
      float p3 = fexp2(sf[ni][3]);
      uint32_t w0 = cvtpk_bf16(p0, p1);
      uint32_t w1 = cvtpk_bf16(p2, p3);
      if (ni < 2) { pa0u.u[ni * 2] = w0; pa0u.u[ni * 2 + 1] = w1; }
      else        { pa1u.u[(ni - 2) * 2] = w0; pa1u.u[(ni - 2) * 2 + 1] = w1; }
    }

    __builtin_amdgcn_s_setprio(1);
#pragma unroll
    for (int nd = 0; nd < 4; ++nd) {
      s16x8 v0 = *(const s16x8*)(Lb + 8192 + off0[nd]);
      s16x8 v1 = *(const s16x8*)(Lb + 8192 + (off0[nd] ^ 64));
      oacc[nd] = __builtin_amdgcn_mfma_f32_16x16x32_bf16(pa0u.v, v0, oacc[nd], 0, 0, 0);
      oacc[nd] = __builtin_amdgcn_mfma_f32_16x16x32_bf16(pa1u.v, v1, oacc[nd], 0, 0, 0);
    }
    oextra = __builtin_amdgcn_mfma_f32_16x16x32_bf16(pa0u.v, bones, oextra, 0, 0, 0);
    oextra = __builtin_amdgcn_mfma_f32_16x16x32_bf16(pa1u.v, bones, oextra, 0, 0, 0);
    __builtin_amdgcn_s_setprio(0);

    ++cur; if (cur == 3) cur = 0;
  }

  float linv[4];
#pragma unroll
  for (int r = 0; r < 4; ++r) linv[r] = 1.f / oextra[r];
#pragma unroll
  for (int nd = 0; nd < 4; ++nd)
#pragma unroll
    for (int r = 0; r < 4; ++r) {
      int qrow = q0 + w * 16 + lc * 4 + r;
      ob[qkbase + (size_t)qrow * 1024 + nd * 16 + lr] = f2bf(oacc[nd][r] * linv[r]);
    }
#undef STAGE
}

// ---------------- launch ----------------
extern "C" void kernel_launch(void* const* d_in, const int* in_sizes, int n_in,
                              void* d_out, int out_size, void* d_ws, size_t ws_size,
                              hipStream_t stream) {
  const float* query = (const float*)d_in[0];
  const float* key_  = (const float*)d_in[1];
  const float* value = (const float*)d_in[2];
  const float* Wq = (const float*)d_in[3];
  const float* bq = (const float*)d_in[4];
  const float* Wk = (const float*)d_in[5];
  const float* bk = (const float*)d_in[6];
  const float* Wv = (const float*)d_in[7];
  const float* bv = (const float*)d_in[8];
  const float* Wo = (const float*)d_in[9];
  const float* bo = (const float*)d_in[10];

  const int MS = 4 * 2048;            // B*S = 8192
  const int D = 1024;
  const size_t NX = (size_t)MS * D;   // 8388608
  const size_t NW = (size_t)D * D;    // 1048576

  const size_t need = (6 * NX + 4 * NW) * 2;
  if (ws_size < need) return;

  unsigned short* ws  = (unsigned short*)d_ws;
  unsigned short* xq  = ws;
  unsigned short* xk  = xq + NX;
  unsigned short* xv  = xk + NX;
  unsigned short* qb_ = xv + NX;
  unsigned short* kb_ = qb_ + NX;
  unsigned short* vtb = kb_ + NX;     // V^T [1024][8192]
  unsigned short* wqb = vtb + NX;
  unsigned short* wkb = wqb + NW;
  unsigned short* wvb = wkb + NW;
  unsigned short* wob = wvb + NW;
  unsigned short* attn = xq;          // q-GEMM consumed xq before attention

  CvtJobs cj;
  cj.src[0] = query; cj.dst[0] = xq;  cj.n4[0] = (int)(NX / 4);
  cj.src[1] = key_;  cj.dst[1] = xk;  cj.n4[1] = (int)(NX / 4);
  cj.src[2] = value; cj.dst[2] = xv;  cj.n4[2] = (int)(NX / 4);
  cj.src[3] = Wq;    cj.dst[3] = wqb; cj.n4[3] = (int)(NW / 4);
  cj.src[4] = Wk;    cj.dst[4] = wkb; cj.n4[4] = (int)(NW / 4);
  cj.src[5] = Wv;    cj.dst[5] = wvb; cj.n4[5] = (int)(NW / 4);
  cj.src[6] = Wo;    cj.dst[6] = wob; cj.n4[6] = (int)(NW / 4);
  cvt_all<<<dim3(1024, 7), 256, 0, stream>>>(cj);

  const float qscale = 0.18033688f;   // 0.125 * log2(e)
  GemmJob jq = { xq,  wqb, bq, qb_, MS, D,  4,  0, qscale };
  GemmJob jk = { xk,  wkb, bk, kb_, MS, D,  4,  0, 1.f };
  GemmJob jv = { wvb, xv,  bv, vtb, D,  MS, 32, 1, 1.f };  // V^T out
  gemm_qkv<<<dim3(384), 512, 0, stream>>>(jq, jk, jv);

  attn_fwd<<<dim3(1024), 512, 0, stream>>>(qb_, kb_, vtb, attn);

  gemm_out<<<dim3(128), 512, 0, stream>>>(attn, wob, bo, (float*)d_out, MS, D, D);
}

// Round 15
// 207.869 us; speedup vs baseline: 1.0021x; 1.0021x over previous
//
#include <hip/hip_runtime.h>
#include <stdint.h>

typedef __attribute__((ext_vector_type(8))) short  s16x8;
typedef __attribute__((ext_vector_type(4))) float  f32x4;
typedef __attribute__((ext_vector_type(16))) float f32x16;
typedef __attribute__((ext_vector_type(4))) unsigned short u16x4;

__device__ __forceinline__ unsigned short f2bf(float f) {
  union { float f; uint32_t u; } x; x.f = f;
  uint32_t u = x.u;
  return (unsigned short)((u + 0x7fffu + ((u >> 16) & 1u)) >> 16);
}

__device__ __forceinline__ float fexp2(float x) {
  float r; asm("v_exp_f32 %0, %1" : "=v"(r) : "v"(x)); return r;
}
__device__ __forceinline__ uint32_t cvtpk_bf16(float lo, float hi) {
  uint32_t r; asm("v_cvt_pk_bf16_f32 %0, %1, %2" : "=v"(r) : "v"(lo), "v"(hi)); return r;
}

__device__ __forceinline__ void gload_lds16(const void* g, void* l) {
  __builtin_amdgcn_global_load_lds(
      (const __attribute__((address_space(1))) void*)g,
      (__attribute__((address_space(3))) void*)l, 16, 0, 0);
}

// ---------------- fused fp32 -> bf16 converts (7 jobs, one launch) ----------
struct CvtJobs {
  const float* src[7];
  unsigned short* dst[7];
  int n4[7];
};
__global__ __launch_bounds__(256) void cvt_all(CvtJobs jobs) {
  const int j = blockIdx.y;
  const float* __restrict__ src = jobs.src[j];
  unsigned short* __restrict__ dst = jobs.dst[j];
  const int n4 = jobs.n4[j];
  const int stride = gridDim.x * blockDim.x;
  for (int i = blockIdx.x * blockDim.x + threadIdx.x; i < n4; i += stride) {
    f32x4 v = *(const f32x4*)(src + (size_t)i * 4);
    u16x4 o = { f2bf(v[0]), f2bf(v[1]), f2bf(v[2]), f2bf(v[3]) };
    *(u16x4*)(dst + (size_t)i * 4) = o;
  }
}

// ---------------- bf16 GEMM core (C = A @ B^T), 128x128 tile, BK=32 --------
// 4 waves (2x2), wave tile 64x64 via 2x2 MFMA 32x32x16 (8 MFMA + 8 ds_read
// per K-step; 15% fewer matrix-pipe cycles vs 16x16x32). DOUBLE-buffered
// LDS (2x16KB), T3-minimum schedule: {STAGE(t+1) -> ds_read(t) -> MFMA ->
// vmcnt(0)+barrier}. Existing sigma(row)=(row>>1)&3 chunk swizzle gives
// 2-way residual (free) for the 32-row read span as well.
struct GemmJob {
  const unsigned short* A;
  const unsigned short* Bmat;
  const float* bias;
  unsigned short* C;
  int M, N, Nb;
  int bias_row;
  float scale;
};

__device__ __forceinline__ void gemm_core32(const unsigned short* __restrict__ A,
                                            const unsigned short* __restrict__ Bw,
                                            int m0, int n0, int K, char* L,
                                            f32x16 (&acc)[2][2]) {
  const int tid = threadIdx.x;
  const int l = tid & 63;
  const int lm = l & 31, l5 = l >> 5;
  const int w = tid >> 6;
  const int wr = w >> 1, wc = w & 1;

  const int srow = tid >> 2;
  const int sc = (tid & 3) ^ ((srow >> 1) & 3);   // pre-swizzled source chunk
  const unsigned short* sA1 = A + (size_t)(m0 + srow) * K + sc * 8;
  const unsigned short* sA2 = A + (size_t)(m0 + srow + 64) * K + sc * 8;
  const unsigned short* sB1 = Bw + (size_t)(n0 + srow) * K + sc * 8;
  const unsigned short* sB2 = Bw + (size_t)(n0 + srow + 64) * K + sc * 8;
  char* d1 = L + (size_t)tid * 16;          // A rows [0,64)
  char* d2 = d1 + 4096;                     // A rows [64,128)
  char* d3 = d1 + 8192;                     // B rows [0,64)
  char* d4 = d1 + 12288;                    // B rows [64,128)

#define GSTAGE(BUF, KS) { gload_lds16(sA1 + (KS), d1 + (BUF) * 16384); \
                          gload_lds16(sA2 + (KS), d2 + (BUF) * 16384); \
                          gload_lds16(sB1 + (KS), d3 + (BUF) * 16384); \
                          gload_lds16(sB2 + (KS), d4 + (BUF) * 16384); }

  // fragment offsets: A row = wr*64+i*32+lm, k-chunk = 2s + l5, swizzled
  const int sig = (lm >> 1) & 3;
  int offA[2][2], offB[2][2];
#pragma unroll
  for (int i = 0; i < 2; ++i)
#pragma unroll
    for (int s = 0; s < 2; ++s) {
      offA[i][s] = (wr * 64 + i * 32 + lm) * 64 + (((2 * s + l5) ^ sig) << 4);
      offB[i][s] = 8192 + (wc * 64 + i * 32 + lm) * 64 + (((2 * s + l5) ^ sig) << 4);
    }

  const int nk = K >> 5;
  GSTAGE(0, 0);
  asm volatile("s_waitcnt vmcnt(0)" ::: "memory");
  __builtin_amdgcn_s_barrier();
  int cur = 0;
  for (int t = 0; t < nk; ++t) {
    if (t + 1 < nk) GSTAGE(cur ^ 1, (t + 1) * 32);   // prefetch next tile
    const char* Lb = L + cur * 16384;
    s16x8 af[2][2], bfr[2][2];
#pragma unroll
    for (int i = 0; i < 2; ++i)
#pragma unroll
      for (int s = 0; s < 2; ++s) {
        af[i][s] = *(const s16x8*)(Lb + offA[i][s]);
        bfr[i][s] = *(const s16x8*)(Lb + offB[i][s]);
      }
    __builtin_amdgcn_s_setprio(1);
#pragma unroll
    for (int i = 0; i < 2; ++i)
#pragma unroll
      for (int j = 0; j < 2; ++j) {
        acc[i][j] = __builtin_amdgcn_mfma_f32_32x32x16_bf16(af[i][0], bfr[j][0], acc[i][j], 0, 0, 0);
        acc[i][j] = __builtin_amdgcn_mfma_f32_32x32x16_bf16(af[i][1], bfr[j][1], acc[i][j], 0, 0, 0);
      }
    __builtin_amdgcn_s_setprio(0);
    asm volatile("s_waitcnt vmcnt(0)" ::: "memory");  // next tile resident
    __builtin_amdgcn_s_barrier();                     // all waves done with cur
    cur ^= 1;
  }
#undef GSTAGE
}

// fused Q/K/V projection GEMMs, XCD-chunked 1D grid (1536 blocks)
__global__ __launch_bounds__(256) void gemm_qkv(GemmJob j0, GemmJob j1, GemmJob j2) {
  __shared__ __align__(16) char L[32768];
  const int f = blockIdx.x;
  const int wid = (f & 7) * 192 + (f >> 3);
  const int job = wid >> 9;
  const int i = wid & 511;
  const GemmJob jb = (job == 0) ? j0 : (job == 1) ? j1 : j2;
  const int m0 = (i / jb.Nb) * 128, n0 = (i % jb.Nb) * 128;
  f32x16 acc[2][2];
#pragma unroll
  for (int i2 = 0; i2 < 2; ++i2)
#pragma unroll
    for (int j2 = 0; j2 < 2; ++j2)
#pragma unroll
      for (int e = 0; e < 16; ++e) acc[i2][j2][e] = 0.f;
  gemm_core32(jb.A, jb.Bmat, m0, n0, 1024, L, acc);
  const int tid = threadIdx.x;
  const int l = tid & 63, w = tid >> 6;
  const int lm = l & 31, l5 = l >> 5;
  const int wr = w >> 1, wc = w & 1;
#pragma unroll
  for (int i2 = 0; i2 < 2; ++i2) {
#pragma unroll
    for (int j2 = 0; j2 < 2; ++j2) {
      const int col = n0 + wc * 64 + j2 * 32 + lm;
      float bcol = jb.bias_row ? 0.f : jb.bias[col];
#pragma unroll
      for (int g = 0; g < 4; ++g) {
        const int row0 = m0 + wr * 64 + i2 * 32 + l5 * 4 + g * 8;
        f32x4 brow;
        if (jb.bias_row) brow = *(const f32x4*)&jb.bias[row0];
#pragma unroll
        for (int r = 0; r < 4; ++r) {
          float v = (acc[i2][j2][g * 4 + r] + (jb.bias_row ? brow[r] : bcol)) * jb.scale;
          jb.C[(size_t)(row0 + r) * jb.N + col] = f2bf(v);
        }
      }
    }
  }
}

// output projection GEMM (fp32 out, col bias), XCD-chunked 1D grid (512)
__global__ __launch_bounds__(256) void gemm_out(const unsigned short* __restrict__ A,
                                                const unsigned short* __restrict__ Bw,
                                                const float* __restrict__ bias,
                                                float* __restrict__ Cout,
                                                int M, int N, int K) {
  __shared__ __align__(16) char L[32768];
  const int f = blockIdx.x;
  const int wid = (f & 7) * 64 + (f >> 3);
  const int m0 = (wid >> 3) * 128, n0 = (wid & 7) * 128;
  f32x16 acc[2][2];
#pragma unroll
  for (int i = 0; i < 2; ++i)
#pragma unroll
    for (int j = 0; j < 2; ++j)
#pragma unroll
      for (int e = 0; e < 16; ++e) acc[i][j][e] = 0.f;
  gemm_core32(A, Bw, m0, n0, K, L, acc);
  const int tid = threadIdx.x;
  const int l = tid & 63, w = tid >> 6;
  const int lm = l & 31, l5 = l >> 5;
  const int wr = w >> 1, wc = w & 1;
#pragma unroll
  for (int i = 0; i < 2; ++i) {
#pragma unroll
    for (int j = 0; j < 2; ++j) {
      const int col = n0 + wc * 64 + j * 32 + lm;
      float bcol = bias[col];
#pragma unroll
      for (int g = 0; g < 4; ++g) {
        const int row0 = m0 + wr * 64 + i * 32 + l5 * 4 + g * 8;
#pragma unroll
        for (int r = 0; r < 4; ++r)
          Cout[(size_t)(row0 + r) * N + col] = acc[i][j][g * 4 + r] + bcol;
      }
    }
  }
}

// ---------------- flash attention: B=4,S=2048,H=16,HD=64 ----------------
// (byte-identical to R13 — issue-saturated at 46% Mfma + 46% VALU)
__global__ __launch_bounds__(512) void attn_fwd(const unsigned short* __restrict__ qb,
                                                const unsigned short* __restrict__ kb,
                                                const unsigned short* __restrict__ vtb,
                                                unsigned short* __restrict__ ob) {
  __shared__ __align__(16) unsigned short L[3 * 8192];
  const int tid = threadIdx.x;
  const int l = tid & 63, w = tid >> 6;
  const int lr = l & 15, lc = l >> 4;
  const int i0 = blockIdx.x;
  const int wid = (i0 & 7) * 128 + (i0 >> 3);
  const int qx = wid & 15;
  const int h = (wid >> 4) & 15;
  const int b = wid >> 8;
  const int q0 = qx * 128;
  const size_t qkbase = ((size_t)b * 2048) * 1024 + (size_t)h * 64;
  const size_t vtbase = (size_t)(h * 64) * 8192 + (size_t)b * 2048;

  s16x8 aq0, aq1;
  {
    const unsigned short* qp = qb + qkbase + (size_t)(q0 + w * 16 + lr) * 1024 + lc * 8;
    aq0 = *(const s16x8*)qp;
    aq1 = *(const s16x8*)(qp + 32);
  }

  union { u16x4 h4[2]; s16x8 v; } onesu;
#pragma unroll
  for (int i = 0; i < 2; ++i) onesu.h4[i] = (u16x4){0x3F80, 0x3F80, 0x3F80, 0x3F80};
  const s16x8 bones = onesu.v;

  f32x4 oacc[4];
  f32x4 oextra = (f32x4){0.f, 0.f, 0.f, 0.f};
#pragma unroll
  for (int nd = 0; nd < 4; ++nd) oacc[nd] = (f32x4){0.f, 0.f, 0.f, 0.f};

  const int role = w >> 2, wk = w & 3;
  const int rl = l >> 3;
  const int cs = (l & 7) ^ rl;
  const int rA = wk * 16 + rl, rB = rA + 8;
#define RHO(rr) (8 * (((rr) >> 2) & 3) + 4 * (((rr) >> 4) & 1) + ((rr) & 3) + 32 * ((rr) >> 5))
  const unsigned short* sA;
  const unsigned short* sB;
  size_t tstep;
  if (role == 0) {
    sA = kb + qkbase + (size_t)RHO(rA) * 1024 + cs * 8;
    sB = kb + qkbase + (size_t)RHO(rB) * 1024 + cs * 8;
    tstep = (size_t)64 * 1024;
  } else {
    sA = vtb + vtbase + (size_t)rA * 8192 + cs * 8;
    sB = vtb + vtbase + (size_t)rB * 8192 + cs * 8;
    tstep = 64;
  }
#undef RHO
  char* dstL = (char*)L + role * 8192 + wk * 2048 + l * 16;

#define STAGE(BUF, T) {                                              \
    gload_lds16(sA + (size_t)(T) * tstep, dstL + (BUF) * 16384);     \
    gload_lds16(sB + (size_t)(T) * tstep, dstL + (BUF) * 16384 + 1024); }

  int off0[4];
#pragma unroll
  for (int ni = 0; ni < 4; ++ni)
    off0[ni] = (ni * 16 + lr) * 128 + ((lc ^ (lr & 7)) * 16);

  STAGE(0, 0);
  STAGE(1, 1);

  int cur = 0;
  for (int t = 0; t < 32; ++t) {
    if (t < 31) asm volatile("s_waitcnt vmcnt(2)" ::: "memory");
    else        asm volatile("s_waitcnt vmcnt(0)" ::: "memory");
    __builtin_amdgcn_s_barrier();
    if (t < 30) {
      int nb = cur + 2; if (nb >= 3) nb -= 3;
      STAGE(nb, t + 2);
    }
    const char* Lb = (const char*)L + cur * 16384;

    f32x4 sf[4];
    __builtin_amdgcn_s_setprio(1);
#pragma unroll
    for (int ni = 0; ni < 4; ++ni) {
      s16x8 k0 = *(const s16x8*)(Lb + off0[ni]);
      s16x8 k1 = *(const s16x8*)(Lb + (off0[ni] ^ 64));
      f32x4 z = (f32x4){0.f, 0.f, 0.f, 0.f};
      z = __builtin_amdgcn_mfma_f32_16x16x32_bf16(k0, aq0, z, 0, 0, 0);
      z = __builtin_amdgcn_mfma_f32_16x16x32_bf16(k1, aq1, z, 0, 0, 0);
      sf[ni] = z;
    }
    __builtin_amdgcn_s_setprio(0);

    union { uint32_t u[4]; s16x8 v; } pa0u, pa1u;
#pragma unroll
    for (int ni = 0; ni < 4; ++ni) {
      float p0 = fexp2(sf[ni][0]);
      float p1 = fexp2(sf[ni][1]);
      float p2 = fexp2(sf[ni][2]);
      float p3 = fexp2(sf[ni][3]);
      uint32_t w0 = cvtpk_bf16(p0, p1);
      uint32_t w1 = cvtpk_bf16(p2, p3);
      if (ni < 2) { pa0u.u[ni * 2] = w0; pa0u.u[ni * 2 + 1] = w1; }
      else        { pa1u.u[(ni - 2) * 2] = w0; pa1u.u[(ni - 2) * 2 + 1] = w1; }
    }

    __builtin_amdgcn_s_setprio(1);
#pragma unroll
    for (int nd = 0; nd < 4; ++nd) {
      s16x8 v0 = *(const s16x8*)(Lb + 8192 + off0[nd]);
      s16x8 v1 = *(const s16x8*)(Lb + 8192 + (off0[nd] ^ 64));
      oacc[nd] = __builtin_amdgcn_mfma_f32_16x16x32_bf16(pa0u.v, v0, oacc[nd], 0, 0, 0);
      oacc[nd] = __builtin_amdgcn_mfma_f32_16x16x32_bf16(pa1u.v, v1, oacc[nd], 0, 0, 0);
    }
    oextra = __builtin_amdgcn_mfma_f32_16x16x32_bf16(pa0u.v, bones, oextra, 0, 0, 0);
    oextra = __builtin_amdgcn_mfma_f32_16x16x32_bf16(pa1u.v, bones, oextra, 0, 0, 0);
    __builtin_amdgcn_s_setprio(0);

    ++cur; if (cur == 3) cur = 0;
  }

  float linv[4];
#pragma unroll
  for (int r = 0; r < 4; ++r) linv[r] = 1.f / oextra[r];
#pragma unroll
  for (int nd = 0; nd < 4; ++nd)
#pragma unroll
    for (int r = 0; r < 4; ++r) {
      int qrow = q0 + w * 16 + lc * 4 + r;
      ob[qkbase + (size_t)qrow * 1024 + nd * 16 + lr] = f2bf(oacc[nd][r] * linv[r]);
    }
#undef STAGE
}

// ---------------- launch ----------------
extern "C" void kernel_launch(void* const* d_in, const int* in_sizes, int n_in,
                              void* d_out, int out_size, void* d_ws, size_t ws_size,
                              hipStream_t stream) {
  const float* query = (const float*)d_in[0];
  const float* key_  = (const float*)d_in[1];
  const float* value = (const float*)d_in[2];
  const float* Wq = (const float*)d_in[3];
  const float* bq = (const float*)d_in[4];
  const float* Wk = (const float*)d_in[5];
  const float* bk = (const float*)d_in[6];
  const float* Wv = (const float*)d_in[7];
  const float* bv = (const float*)d_in[8];
  const float* Wo = (const float*)d_in[9];
  const float* bo = (const float*)d_in[10];

  const int MS = 4 * 2048;            // B*S = 8192
  const int D = 1024;
  const size_t NX = (size_t)MS * D;   // 8388608
  const size_t NW = (size_t)D * D;    // 1048576

  const size_t need = (6 * NX + 4 * NW) * 2;
  if (ws_size < need) return;

  unsigned short* ws  = (unsigned short*)d_ws;
  unsigned short* xq  = ws;
  unsigned short* xk  = xq + NX;
  unsigned short* xv  = xk + NX;
  unsigned short* qb_ = xv + NX;
  unsigned short* kb_ = qb_ + NX;
  unsigned short* vtb = kb_ + NX;     // V^T [1024][8192]
  unsigned short* wqb = vtb + NX;
  unsigned short* wkb = wqb + NW;
  unsigned short* wvb = wkb + NW;
  unsigned short* wob = wvb + NW;
  unsigned short* attn = xq;          // q-GEMM consumed xq before attention

  CvtJobs cj;
  cj.src[0] = query; cj.dst[0] = xq;  cj.n4[0] = (int)(NX / 4);
  cj.src[1] = key_;  cj.dst[1] = xk;  cj.n4[1] = (int)(NX / 4);
  cj.src[2] = value; cj.dst[2] = xv;  cj.n4[2] = (int)(NX / 4);
  cj.src[3] = Wq;    cj.dst[3] = wqb; cj.n4[3] = (int)(NW / 4);
  cj.src[4] = Wk;    cj.dst[4] = wkb; cj.n4[4] = (int)(NW / 4);
  cj.src[5] = Wv;    cj.dst[5] = wvb; cj.n4[5] = (int)(NW / 4);
  cj.src[6] = Wo;    cj.dst[6] = wob; cj.n4[6] = (int)(NW / 4);
  cvt_all<<<dim3(1024, 7), 256, 0, stream>>>(cj);

  const float qscale = 0.18033688f;   // 0.125 * log2(e)
  GemmJob jq = { xq,  wqb, bq, qb_, MS, D,  D / 128,  0, qscale };
  GemmJob jk = { xk,  wkb, bk, kb_, MS, D,  D / 128,  0, 1.f };
  GemmJob jv = { wvb, xv,  bv, vtb, D,  MS, MS / 128, 1, 1.f };  // V^T out
  gemm_qkv<<<dim3(1536), 256, 0, stream>>>(jq, jk, jv);

  attn_fwd<<<dim3(1024), 512, 0, stream>>>(qb_, kb_, vtb, attn);

  gemm_out<<<dim3(512), 256, 0, stream>>>(attn, wob, bo, (float*)d_out, MS, D, D);
}

// Round 16
// 201.324 us; speedup vs baseline: 1.0347x; 1.0325x over previous
//
#include <hip/hip_runtime.h>
#include <stdint.h>

typedef __attribute__((ext_vector_type(8))) short  s16x8;
typedef __attribute__((ext_vector_type(4))) float  f32x4;
typedef __attribute__((ext_vector_type(4))) unsigned short u16x4;

__device__ __forceinline__ unsigned short f2bf(float f) {
  union { float f; uint32_t u; } x; x.f = f;
  uint32_t u = x.u;
  return (unsigned short)((u + 0x7fffu + ((u >> 16) & 1u)) >> 16);
}

__device__ __forceinline__ float fexp2(float x) {
  float r; asm("v_exp_f32 %0, %1" : "=v"(r) : "v"(x)); return r;
}
__device__ __forceinline__ uint32_t cvtpk_bf16(float lo, float hi) {
  uint32_t r; asm("v_cvt_pk_bf16_f32 %0, %1, %2" : "=v"(r) : "v"(lo), "v"(hi)); return r;
}

__device__ __forceinline__ void gload_lds16(const void* g, void* l) {
  __builtin_amdgcn_global_load_lds(
      (const __attribute__((address_space(1))) void*)g,
      (__attribute__((address_space(3))) void*)l, 16, 0, 0);
}

// ---------------- fused fp32 -> bf16 converts (7 jobs, one launch) ----------
struct CvtJobs {
  const float* src[7];
  unsigned short* dst[7];
  int n4[7];
};
__global__ __launch_bounds__(256) void cvt_all(CvtJobs jobs) {
  const int j = blockIdx.y;
  const float* __restrict__ src = jobs.src[j];
  unsigned short* __restrict__ dst = jobs.dst[j];
  const int n4 = jobs.n4[j];
  const int stride = gridDim.x * blockDim.x;
  for (int i = blockIdx.x * blockDim.x + threadIdx.x; i < n4; i += stride) {
    f32x4 v = *(const f32x4*)(src + (size_t)i * 4);
    u16x4 o = { f2bf(v[0]), f2bf(v[1]), f2bf(v[2]), f2bf(v[3]) };
    *(u16x4*)(dst + (size_t)i * 4) = o;
  }
}

// ---------------- bf16 GEMM core (C = A @ B^T), 128x128 tile, BK=32 --------
// (R13 proven best: 4 waves 2x2, wave tile 64x64, acc[4][4], 2-buffer LDS,
// T3-minimum schedule, both-sides XOR swizzle, setprio.)
struct GemmJob {
  const unsigned short* A;
  const unsigned short* Bmat;
  const float* bias;
  unsigned short* C;
  int M, N, Nb;
  int bias_row;
  float scale;
};

__device__ __forceinline__ void gemm_core4(const unsigned short* __restrict__ A,
                                           const unsigned short* __restrict__ Bw,
                                           int m0, int n0, int K, char* L,
                                           f32x4 (&acc)[4][4]) {
  const int tid = threadIdx.x;
  const int l = tid & 63;
  const int lr = l & 15, lc = l >> 4;
  const int w = tid >> 6;
  const int wr = w >> 1, wc = w & 1;

  const int srow = tid >> 2;
  const int sc = (tid & 3) ^ ((srow >> 1) & 3);   // pre-swizzled source chunk
  const unsigned short* sA1 = A + (size_t)(m0 + srow) * K + sc * 8;
  const unsigned short* sA2 = A + (size_t)(m0 + srow + 64) * K + sc * 8;
  const unsigned short* sB1 = Bw + (size_t)(n0 + srow) * K + sc * 8;
  const unsigned short* sB2 = Bw + (size_t)(n0 + srow + 64) * K + sc * 8;
  char* d1 = L + (size_t)tid * 16;          // A rows [0,64)
  char* d2 = d1 + 4096;                     // A rows [64,128)
  char* d3 = d1 + 8192;                     // B rows [0,64)
  char* d4 = d1 + 12288;                    // B rows [64,128)

#define GSTAGE(BUF, KS) { gload_lds16(sA1 + (KS), d1 + (BUF) * 16384); \
                          gload_lds16(sA2 + (KS), d2 + (BUF) * 16384); \
                          gload_lds16(sB1 + (KS), d3 + (BUF) * 16384); \
                          gload_lds16(sB2 + (KS), d4 + (BUF) * 16384); }

  const int s16 = (lc ^ ((lr >> 1) & 3)) * 16;
  int offA[4], offB[4];
#pragma unroll
  for (int i = 0; i < 4; ++i) offA[i] = (wr * 64 + i * 16 + lr) * 64 + s16;
#pragma unroll
  for (int j = 0; j < 4; ++j) offB[j] = 8192 + (wc * 64 + j * 16 + lr) * 64 + s16;

  const int nk = K >> 5;
  GSTAGE(0, 0);
  asm volatile("s_waitcnt vmcnt(0)" ::: "memory");
  __builtin_amdgcn_s_barrier();
  int cur = 0;
  for (int t = 0; t < nk; ++t) {
    if (t + 1 < nk) GSTAGE(cur ^ 1, (t + 1) * 32);   // prefetch next tile
    const char* Lb = L + cur * 16384;
    s16x8 af[4], bfr[4];
#pragma unroll
    for (int i = 0; i < 4; ++i) af[i] = *(const s16x8*)(Lb + offA[i]);
#pragma unroll
    for (int j = 0; j < 4; ++j) bfr[j] = *(const s16x8*)(Lb + offB[j]);
    __builtin_amdgcn_s_setprio(1);
#pragma unroll
    for (int i = 0; i < 4; ++i)
#pragma unroll
      for (int j = 0; j < 4; ++j)
        acc[i][j] = __builtin_amdgcn_mfma_f32_16x16x32_bf16(af[i], bfr[j], acc[i][j], 0, 0, 0);
    __builtin_amdgcn_s_setprio(0);
    asm volatile("s_waitcnt vmcnt(0)" ::: "memory");  // next tile resident
    __builtin_amdgcn_s_barrier();                     // all waves done with cur
    cur ^= 1;
  }
#undef GSTAGE
}

// fused Q/K/V projection GEMMs, XCD-chunked 1D grid (1536 blocks)
__global__ __launch_bounds__(256) void gemm_qkv(GemmJob j0, GemmJob j1, GemmJob j2) {
  __shared__ __align__(16) char L[32768];
  const int f = blockIdx.x;
  const int wid = (f & 7) * 192 + (f >> 3);
  const int job = wid >> 9;
  const int i = wid & 511;
  const GemmJob jb = (job == 0) ? j0 : (job == 1) ? j1 : j2;
  const int m0 = (i / jb.Nb) * 128, n0 = (i % jb.Nb) * 128;
  f32x4 acc[4][4];
#pragma unroll
  for (int i2 = 0; i2 < 4; ++i2)
#pragma unroll
    for (int j2 = 0; j2 < 4; ++j2) acc[i2][j2] = (f32x4){0.f, 0.f, 0.f, 0.f};
  gemm_core4(jb.A, jb.Bmat, m0, n0, 1024, L, acc);
  const int tid = threadIdx.x;
  const int l = tid & 63, w = tid >> 6;
  const int lr = l & 15, lc = l >> 4;
  const int wr = w >> 1, wc = w & 1;
#pragma unroll
  for (int i2 = 0; i2 < 4; ++i2) {
    const int row0 = m0 + wr * 64 + i2 * 16 + lc * 4;
    f32x4 brow;
    if (jb.bias_row) brow = *(const f32x4*)&jb.bias[row0];
#pragma unroll
    for (int j2 = 0; j2 < 4; ++j2) {
      const int col = n0 + wc * 64 + j2 * 16 + lr;
      float bcol = jb.bias_row ? 0.f : jb.bias[col];
#pragma unroll
      for (int r = 0; r < 4; ++r) {
        float v = (acc[i2][j2][r] + (jb.bias_row ? brow[r] : bcol)) * jb.scale;
        jb.C[(size_t)(row0 + r) * jb.N + col] = f2bf(v);
      }
    }
  }
}

// output projection GEMM (fp32 out, col bias), XCD-chunked 1D grid (512)
__global__ __launch_bounds__(256) void gemm_out(const unsigned short* __restrict__ A,
                                                const unsigned short* __restrict__ Bw,
                                                const float* __restrict__ bias,
                                                float* __restrict__ Cout,
                                                int M, int N, int K) {
  __shared__ __align__(16) char L[32768];
  const int f = blockIdx.x;
  const int wid = (f & 7) * 64 + (f >> 3);
  const int m0 = (wid >> 3) * 128, n0 = (wid & 7) * 128;
  f32x4 acc[4][4];
#pragma unroll
  for (int i = 0; i < 4; ++i)
#pragma unroll
    for (int j = 0; j < 4; ++j) acc[i][j] = (f32x4){0.f, 0.f, 0.f, 0.f};
  gemm_core4(A, Bw, m0, n0, K, L, acc);
  const int tid = threadIdx.x;
  const int l = tid & 63, w = tid >> 6;
  const int lr = l & 15, lc = l >> 4;
  const int wr = w >> 1, wc = w & 1;
#pragma unroll
  for (int i = 0; i < 4; ++i) {
    const int row0 = m0 + wr * 64 + i * 16 + lc * 4;
#pragma unroll
    for (int j = 0; j < 4; ++j) {
      const int col = n0 + wc * 64 + j * 16 + lr;
      float bcol = bias[col];
#pragma unroll
      for (int r = 0; r < 4; ++r)
        Cout[(size_t)(row0 + r) * N + col] = acc[i][j][r] + bcol;
    }
  }
}

// ---------------- flash attention: B=4,S=2048,H=16,HD=64 ----------------
// QBLK=256 (8 waves, TWO 16-row q-groups per wave), KVBLK=64, triple-buffered
// LDS, depth-2 prefetch, counted vmcnt + raw s_barrier (T3/T4).
// Two independent q-group chains per wave interleave QK/exp/PV across pipes
// (T15-style overlap without extra pipeline state). Waves 0-3 stage K
// (rho-permuted rows, XOR-swizzled), waves 4-7 stage V^T. Swapped QK^T ->
// in-register P. m=0 softmax; lsum via ones-B MFMA. XCD-chunked swizzle.
__global__ __launch_bounds__(512) void attn_fwd(const unsigned short* __restrict__ qb,
                                                const unsigned short* __restrict__ kb,
                                                const unsigned short* __restrict__ vtb,
                                                unsigned short* __restrict__ ob) {
  __shared__ __align__(16) unsigned short L[3 * 8192];
  const int tid = threadIdx.x;
  const int l = tid & 63, w = tid >> 6;
  const int lr = l & 15, lc = l >> 4;
  const int i0 = blockIdx.x;                 // 512 blocks
  const int wid = (i0 & 7) * 64 + (i0 >> 3); // XCD-chunked
  const int qx = wid & 7;
  const int h = (wid >> 3) & 15;
  const int b = wid >> 7;
  const int q0 = qx * 256;
  const size_t qkbase = ((size_t)b * 2048) * 1024 + (size_t)h * 64;
  const size_t vtbase = (size_t)(h * 64) * 8192 + (size_t)b * 2048;

  s16x8 aq[2][2];
#pragma unroll
  for (int g = 0; g < 2; ++g) {
    const unsigned short* qp = qb + qkbase + (size_t)(q0 + w * 32 + g * 16 + lr) * 1024 + lc * 8;
    aq[g][0] = *(const s16x8*)qp;
    aq[g][1] = *(const s16x8*)(qp + 32);
  }

  union { u16x4 h4[2]; s16x8 v; } onesu;
#pragma unroll
  for (int i = 0; i < 2; ++i) onesu.h4[i] = (u16x4){0x3F80, 0x3F80, 0x3F80, 0x3F80};
  const s16x8 bones = onesu.v;

  f32x4 oacc[2][4];
  f32x4 oextra[2];
#pragma unroll
  for (int g = 0; g < 2; ++g) {
    oextra[g] = (f32x4){0.f, 0.f, 0.f, 0.f};
#pragma unroll
    for (int nd = 0; nd < 4; ++nd) oacc[g][nd] = (f32x4){0.f, 0.f, 0.f, 0.f};
  }

  const int role = w >> 2, wk = w & 3;
  const int rl = l >> 3;
  const int cs = (l & 7) ^ rl;
  const int rA = wk * 16 + rl, rB = rA + 8;
#define RHO(rr) (8 * (((rr) >> 2) & 3) + 4 * (((rr) >> 4) & 1) + ((rr) & 3) + 32 * ((rr) >> 5))
  const unsigned short* sA;
  const unsigned short* sB;
  size_t tstep;
  if (role == 0) {
    sA = kb + qkbase + (size_t)RHO(rA) * 1024 + cs * 8;
    sB = kb + qkbase + (size_t)RHO(rB) * 1024 + cs * 8;
    tstep = (size_t)64 * 1024;
  } else {
    sA = vtb + vtbase + (size_t)rA * 8192 + cs * 8;
    sB = vtb + vtbase + (size_t)rB * 8192 + cs * 8;
    tstep = 64;
  }
#undef RHO
  char* dstL = (char*)L + role * 8192 + wk * 2048 + l * 16;

#define STAGE(BUF, T) {                                              \
    gload_lds16(sA + (size_t)(T) * tstep, dstL + (BUF) * 16384);     \
    gload_lds16(sB + (size_t)(T) * tstep, dstL + (BUF) * 16384 + 1024); }

  int off0[4];
#pragma unroll
  for (int ni = 0; ni < 4; ++ni)
    off0[ni] = (ni * 16 + lr) * 128 + ((lc ^ (lr & 7)) * 16);

  STAGE(0, 0);
  STAGE(1, 1);

  int cur = 0;
  for (int t = 0; t < 32; ++t) {
    if (t < 31) asm volatile("s_waitcnt vmcnt(2)" ::: "memory");
    else        asm volatile("s_waitcnt vmcnt(0)" ::: "memory");
    __builtin_amdgcn_s_barrier();
    if (t < 30) {
      int nb = cur + 2; if (nb >= 3) nb -= 3;
      STAGE(nb, t + 2);
    }
    const char* Lb = (const char*)L + cur * 16384;

    // K fragments (shared by both q-groups)
    s16x8 kf[4][2];
#pragma unroll
    for (int ni = 0; ni < 4; ++ni) {
      kf[ni][0] = *(const s16x8*)(Lb + off0[ni]);
      kf[ni][1] = *(const s16x8*)(Lb + (off0[ni] ^ 64));
    }
    // V fragments
    s16x8 vf[4][2];
#pragma unroll
    for (int nd = 0; nd < 4; ++nd) {
      vf[nd][0] = *(const s16x8*)(Lb + 8192 + off0[nd]);
      vf[nd][1] = *(const s16x8*)(Lb + 8192 + (off0[nd] ^ 64));
    }

    // S^T = K Q^T for both q-groups (independent chains)
    f32x4 sf[2][4];
    __builtin_amdgcn_s_setprio(1);
#pragma unroll
    for (int g = 0; g < 2; ++g)
#pragma unroll
      for (int ni = 0; ni < 4; ++ni) {
        f32x4 z = (f32x4){0.f, 0.f, 0.f, 0.f};
        z = __builtin_amdgcn_mfma_f32_16x16x32_bf16(kf[ni][0], aq[g][0], z, 0, 0, 0);
        z = __builtin_amdgcn_mfma_f32_16x16x32_bf16(kf[ni][1], aq[g][1], z, 0, 0, 0);
        sf[g][ni] = z;
      }
    __builtin_amdgcn_s_setprio(0);

    // per group: exp/pack then PV (+ones) — g0's VALU overlaps g1's MFMA
#pragma unroll
    for (int g = 0; g < 2; ++g) {
      union { uint32_t u[4]; s16x8 v; } pa0u, pa1u;
#pragma unroll
      for (int ni = 0; ni < 4; ++ni) {
        float p0 = fexp2(sf[g][ni][0]);
        float p1 = fexp2(sf[g][ni][1]);
        float p2 = fexp2(sf[g][ni][2]);
        float p3 = fexp2(sf[g][ni][3]);
        uint32_t w0 = cvtpk_bf16(p0, p1);
        uint32_t w1 = cvtpk_bf16(p2, p3);
        if (ni < 2) { pa0u.u[ni * 2] = w0; pa0u.u[ni * 2 + 1] = w1; }
        else        { pa1u.u[(ni - 2) * 2] = w0; pa1u.u[(ni - 2) * 2 + 1] = w1; }
      }
      __builtin_amdgcn_s_setprio(1);
#pragma unroll
      for (int nd = 0; nd < 4; ++nd) {
        oacc[g][nd] = __builtin_amdgcn_mfma_f32_16x16x32_bf16(pa0u.v, vf[nd][0], oacc[g][nd], 0, 0, 0);
        oacc[g][nd] = __builtin_amdgcn_mfma_f32_16x16x32_bf16(pa1u.v, vf[nd][1], oacc[g][nd], 0, 0, 0);
      }
      oextra[g] = __builtin_amdgcn_mfma_f32_16x16x32_bf16(pa0u.v, bones, oextra[g], 0, 0, 0);
      oextra[g] = __builtin_amdgcn_mfma_f32_16x16x32_bf16(pa1u.v, bones, oextra[g], 0, 0, 0);
      __builtin_amdgcn_s_setprio(0);
    }

    ++cur; if (cur == 3) cur = 0;
  }

  // epilogue: oextra[g][r] = lsum for q-row g*16 + lc*4 + r
#pragma unroll
  for (int g = 0; g < 2; ++g) {
    float linv[4];
#pragma unroll
    for (int r = 0; r < 4; ++r) linv[r] = 1.f / oextra[g][r];
#pragma unroll
    for (int nd = 0; nd < 4; ++nd)
#pragma unroll
      for (int r = 0; r < 4; ++r) {
        int qrow = q0 + w * 32 + g * 16 + lc * 4 + r;
        ob[qkbase + (size_t)qrow * 1024 + nd * 16 + lr] = f2bf(oacc[g][nd][r] * linv[r]);
      }
  }
#undef STAGE
}

// ---------------- launch ----------------
extern "C" void kernel_launch(void* const* d_in, const int* in_sizes, int n_in,
                              void* d_out, int out_size, void* d_ws, size_t ws_size,
                              hipStream_t stream) {
  const float* query = (const float*)d_in[0];
  const float* key_  = (const float*)d_in[1];
  const float* value = (const float*)d_in[2];
  const float* Wq = (const float*)d_in[3];
  const float* bq = (const float*)d_in[4];
  const float* Wk = (const float*)d_in[5];
  const float* bk = (const float*)d_in[6];
  const float* Wv = (const float*)d_in[7];
  const float* bv = (const float*)d_in[8];
  const float* Wo = (const float*)d_in[9];
  const float* bo = (const float*)d_in[10];

  const int MS = 4 * 2048;            // B*S = 8192
  const int D = 1024;
  const size_t NX = (size_t)MS * D;   // 8388608
  const size_t NW = (size_t)D * D;    // 1048576

  const size_t need = (6 * NX + 4 * NW) * 2;
  if (ws_size < need) return;

  unsigned short* ws  = (unsigned short*)d_ws;
  unsigned short* xq  = ws;
  unsigned short* xk  = xq + NX;
  unsigned short* xv  = xk + NX;
  unsigned short* qb_ = xv + NX;
  unsigned short* kb_ = qb_ + NX;
  unsigned short* vtb = kb_ + NX;     // V^T [1024][8192]
  unsigned short* wqb = vtb + NX;
  unsigned short* wkb = wqb + NW;
  unsigned short* wvb = wkb + NW;
  unsigned short* wob = wvb + NW;
  unsigned short* attn = xq;          // q-GEMM consumed xq before attention

  CvtJobs cj;
  cj.src[0] = query; cj.dst[0] = xq;  cj.n4[0] = (int)(NX / 4);
  cj.src[1] = key_;  cj.dst[1] = xk;  cj.n4[1] = (int)(NX / 4);
  cj.src[2] = value; cj.dst[2] = xv;  cj.n4[2] = (int)(NX / 4);
  cj.src[3] = Wq;    cj.dst[3] = wqb; cj.n4[3] = (int)(NW / 4);
  cj.src[4] = Wk;    cj.dst[4] = wkb; cj.n4[4] = (int)(NW / 4);
  cj.src[5] = Wv;    cj.dst[5] = wvb; cj.n4[5] = (int)(NW / 4);
  cj.src[6] = Wo;    cj.dst[6] = wob; cj.n4[6] = (int)(NW / 4);
  cvt_all<<<dim3(1024, 7), 256, 0, stream>>>(cj);

  const float qscale = 0.18033688f;   // 0.125 * log2(e)
  GemmJob jq = { xq,  wqb, bq, qb_, MS, D,  D / 128,  0, qscale };
  GemmJob jk = { xk,  wkb, bk, kb_, MS, D,  D / 128,  0, 1.f };
  GemmJob jv = { wvb, xv,  bv, vtb, D,  MS, MS / 128, 1, 1.f };  // V^T out
  gemm_qkv<<<dim3(1536), 256, 0, stream>>>(jq, jk, jv);

  attn_fwd<<<dim3(512), 512, 0, stream>>>(qb_, kb_, vtb, attn);

  gemm_out<<<dim3(512), 256, 0, stream>>>(attn, wob, bo, (float*)d_out, MS, D, D);
}